// Round 3
// baseline (473.964 us; speedup 1.0000x reference)
//
#include <hip/hip_runtime.h>
#include <stdint.h>

#define S_LEN 2048
#define NH 16
#define EMB 1024
#define L2E 1.44269504f

typedef __attribute__((ext_vector_type(8))) short bf16x8;
typedef __attribute__((ext_vector_type(4))) float floatx4;
typedef const __attribute__((address_space(1))) unsigned int* gas_u32p;
typedef __attribute__((address_space(3))) unsigned int* las_u32p;

static __device__ __forceinline__ void gld_lds16(const void* g, void* l) {
  __builtin_amdgcn_global_load_lds((gas_u32p)g, (las_u32p)l, 16, 0, 0);
}

static __device__ __forceinline__ unsigned short f2bf(float f) {
  unsigned int u = __float_as_uint(f);
  unsigned int r = (u + 0x7FFFu + ((u >> 16) & 1u)) >> 16;
  return (unsigned short)r;
}
static __device__ __forceinline__ unsigned short f2bf_fast(float f) {
  return (unsigned short)((__float_as_uint(f) + 0x8000u) >> 16);
}

// shared bias-writer block body: writes 64K float4s starting at block index bb
static __device__ __forceinline__ void bias_block(int bb, int tid,
                                                  const float* __restrict__ lut,
                                                  float* __restrict__ bias_out) {
#pragma unroll 4
  for (int e = 0; e < 256; e++) {
    int i = (bb << 16) + (e << 8) + tid;
    int h = i >> 20;
    int rem = i & 1048575;
    int q = rem >> 9;
    int k4 = (rem & 511) << 2;
    const float* lr = lut + h * 4096 + (k4 - q + 2048);
    floatx4 v = (floatx4){lr[0], lr[1], lr[2], lr[3]};
    __builtin_nontemporal_store(v, (floatx4*)&bias_out[(size_t)i * 4]);
  }
}

// ---------------- fused prep: cast X, transpose 4 weights, build LUT ----------------
__global__ __launch_bounds__(256) void prep_kernel(const float* __restrict__ X,
                                                   const float* __restrict__ Wq,
                                                   const float* __restrict__ Wk,
                                                   const float* __restrict__ Wv,
                                                   const float* __restrict__ Wo,
                                                   const float* __restrict__ rel,
                                                   unsigned short* __restrict__ Xb,
                                                   unsigned short* __restrict__ WT,
                                                   float* __restrict__ lut) {
  __shared__ float tile[32][33];
  const int bid = blockIdx.x, tid = threadIdx.x;
  if (bid < 4096) {
    int i = bid * 256 + tid;
    float4 v = ((const float4*)X)[i];
    ushort4 o;
    o.x = f2bf(v.x); o.y = f2bf(v.y); o.z = f2bf(v.z); o.w = f2bf(v.w);
    ((ushort4*)Xb)[i] = o;
  } else if (bid < 8192) {
    int w = (bid - 4096) >> 10, t = (bid - 4096) & 1023;
    const float* in = (w == 0) ? Wq : (w == 1) ? Wk : (w == 2) ? Wv : Wo;
    unsigned short* o = WT + (size_t)w * 1048576;
    int bx = t & 31, by = t >> 5;
    int tx = tid & 31, ty = tid >> 5;
    int x = bx * 32 + tx, y0 = by * 32 + ty;
#pragma unroll
    for (int j = 0; j < 4; j++)
      tile[ty + 8 * j][tx] = in[(y0 + 8 * j) * EMB + x];
    __syncthreads();
    int x2 = by * 32 + tx, y2 = bx * 32 + ty;
#pragma unroll
    for (int j = 0; j < 4; j++)
      o[(y2 + 8 * j) * EMB + x2] = f2bf(tile[tx][ty + 8 * j]);
  } else {
    int idx = (bid - 8192) * 256 + tid;
    int delta = idx - 2048;
    int bucket = (delta > 0) ? 16 : 0;
    int rp = (delta < 0) ? -delta : delta;
    int bl;
    if (rp < 8) bl = rp;
    else bl = 8 + (rp >= 12) + (rp >= 16) + (rp >= 23) + (rp >= 32) + (rp >= 46) + (rp >= 64) + (rp >= 91);
    bucket += bl;
#pragma unroll
    for (int h = 0; h < NH; h++)
      lut[h * 4096 + idx] = rel[bucket * NH + h];
  }
}

// ---------------- fused QKV GEMM + bias writer part 1 (grid-partitioned) ----------------
__global__ __launch_bounds__(256) void gemm_qkv(const unsigned short* __restrict__ A,
                                                const unsigned short* __restrict__ BT,
                                                unsigned short* __restrict__ oQ,
                                                unsigned short* __restrict__ oK,
                                                unsigned short* __restrict__ oV,
                                                const float* __restrict__ lut,
                                                float* __restrict__ bias_out) {
  __shared__ __align__(16) unsigned short As[128 * 64];
  __shared__ __align__(16) unsigned short Bs[128 * 64];
  const int tid = threadIdx.x;
  const int id = blockIdx.x;
  if (id >= 768) {
    bias_block(id - 768, tid, lut, bias_out);
    return;
  }
  const int wave = tid >> 6, lane = tid & 63;
  const int quad = lane >> 4, lm = lane & 15;
  const int wm = wave & 1, wn = wave >> 1;
  // XCD-aware chunked remap: 768 = 8 xcd * 96; same-mBase blocks land on one XCD's L2
  const int id2 = (id & 7) * 96 + (id >> 3);
  const int mBase = (id2 / 24) * 128, nBase = (id2 % 24) * 128;
  const int gg = (lane & 7) ^ (lane >> 3);
  const int srow = lane >> 3;
  floatx4 acc[4][4];
#pragma unroll
  for (int i = 0; i < 4; i++)
#pragma unroll
    for (int j = 0; j < 4; j++) acc[i][j] = (floatx4){0.f, 0.f, 0.f, 0.f};

  for (int kt = 0; kt < 16; kt++) {
    int k0 = kt * 64;
    __syncthreads();
#pragma unroll
    for (int c = 0; c < 4; c++) {
      int chunk = wave * 4 + c;
      int row = chunk * 8 + srow;
      gld_lds16(&A[(size_t)(mBase + row) * 1024 + k0 + gg * 8], &As[chunk * 512]);
      gld_lds16(&BT[(size_t)(nBase + row) * 1024 + k0 + gg * 8], &Bs[chunk * 512]);
    }
    __syncthreads();
#pragma unroll
    for (int hh = 0; hh < 2; hh++) {
      bf16x8 af[4], bfr[4];
#pragma unroll
      for (int i = 0; i < 4; i++)
        af[i] = *(const bf16x8*)&As[(wm * 64 + i * 16 + lm) * 64 + (((hh << 2) + quad) ^ (lm & 7)) * 8];
#pragma unroll
      for (int j = 0; j < 4; j++)
        bfr[j] = *(const bf16x8*)&Bs[(wn * 64 + j * 16 + lm) * 64 + (((hh << 2) + quad) ^ (lm & 7)) * 8];
#pragma unroll
      for (int i = 0; i < 4; i++)
#pragma unroll
        for (int j = 0; j < 4; j++)
          acc[i][j] = __builtin_amdgcn_mfma_f32_16x16x32_bf16(af[i], bfr[j], acc[i][j], 0, 0, 0);
    }
  }
  const int which = nBase >> 10;  // block-uniform
  if (which == 2) {
#pragma unroll
    for (int i = 0; i < 4; i++)
#pragma unroll
      for (int j = 0; j < 4; j++) {
        int hd = (nBase - 2048) + wn * 64 + j * 16 + lm;
        int h = hd >> 6, d = hd & 63;
        int m = mBase + wm * 64 + i * 16 + quad * 4;
        int b = m >> 11, s = m & 2047;
        union { unsigned short u[4]; uint2 v; } pk;
#pragma unroll
        for (int r = 0; r < 4; r++) pk.u[r] = f2bf(acc[i][j][r]);
        *(uint2*)&oV[(((size_t)(b * NH + h) * 64 + d) * S_LEN) + s] = pk.v;
      }
  } else {
#pragma unroll
    for (int i = 0; i < 4; i++)
#pragma unroll
      for (int j = 0; j < 4; j++)
#pragma unroll
        for (int r = 0; r < 4; r++) {
          int row = mBase + wm * 64 + i * 16 + quad * 4 + r;
          int col = nBase + wn * 64 + j * 16 + lm;
          int b = row >> 11, s = row & 2047;
          int cw = col & 1023;
          int h = cw >> 6, d = cw & 63;
          float v = acc[i][j][r];
          if (which == 0) v *= L2E;  // pre-scale Q for exp2-based softmax
          unsigned short sv = f2bf(v);
          if (which == 0) oQ[(((size_t)(b * NH + h) * S_LEN + s) * 64) + d] = sv;
          else            oK[(((size_t)(b * NH + h) * S_LEN + s) * 64) + d] = sv;
        }
  }
}

// ---------------- GEMM out-proj + bias writer part 2 ----------------
__global__ __launch_bounds__(256) void gemm_out(const unsigned short* __restrict__ A,
                                                const unsigned short* __restrict__ BT,
                                                float* __restrict__ oF,
                                                const float* __restrict__ lut,
                                                float* __restrict__ bias_out) {
  __shared__ __align__(16) unsigned short As[128 * 64];
  __shared__ __align__(16) unsigned short Bs[128 * 64];
  const int tid = threadIdx.x;
  const int id = blockIdx.x;
  if (id >= 256) {
    bias_block(160 + (id - 256), tid, lut, bias_out);
    return;
  }
  const int wave = tid >> 6, lane = tid & 63;
  const int quad = lane >> 4, lm = lane & 15;
  const int wm = wave & 1, wn = wave >> 1;
  // XCD-aware chunked remap: 256 = 8 xcd * 32
  const int id2 = (id & 7) * 32 + (id >> 3);
  const int mBase = (id2 >> 3) * 128, nBase = (id2 & 7) * 128;
  const int gg = (lane & 7) ^ (lane >> 3);
  const int srow = lane >> 3;
  floatx4 acc[4][4];
#pragma unroll
  for (int i = 0; i < 4; i++)
#pragma unroll
    for (int j = 0; j < 4; j++) acc[i][j] = (floatx4){0.f, 0.f, 0.f, 0.f};

  for (int kt = 0; kt < 16; kt++) {
    int k0 = kt * 64;
    __syncthreads();
#pragma unroll
    for (int c = 0; c < 4; c++) {
      int chunk = wave * 4 + c;
      int row = chunk * 8 + srow;
      gld_lds16(&A[(size_t)(mBase + row) * 1024 + k0 + gg * 8], &As[chunk * 512]);
      gld_lds16(&BT[(size_t)(nBase + row) * 1024 + k0 + gg * 8], &Bs[chunk * 512]);
    }
    __syncthreads();
#pragma unroll
    for (int hh = 0; hh < 2; hh++) {
      bf16x8 af[4], bfr[4];
#pragma unroll
      for (int i = 0; i < 4; i++)
        af[i] = *(const bf16x8*)&As[(wm * 64 + i * 16 + lm) * 64 + (((hh << 2) + quad) ^ (lm & 7)) * 8];
#pragma unroll
      for (int j = 0; j < 4; j++)
        bfr[j] = *(const bf16x8*)&Bs[(wn * 64 + j * 16 + lm) * 64 + (((hh << 2) + quad) ^ (lm & 7)) * 8];
#pragma unroll
      for (int i = 0; i < 4; i++)
#pragma unroll
        for (int j = 0; j < 4; j++)
          acc[i][j] = __builtin_amdgcn_mfma_f32_16x16x32_bf16(af[i], bfr[j], acc[i][j], 0, 0, 0);
    }
  }
#pragma unroll
  for (int i = 0; i < 4; i++)
#pragma unroll
    for (int j = 0; j < 4; j++)
#pragma unroll
      for (int r = 0; r < 4; r++) {
        int row = mBase + wm * 64 + i * 16 + quad * 4 + r;
        int col = nBase + wn * 64 + j * 16 + lm;
        oF[(size_t)row * 1024 + col] = acc[i][j][r];
      }
}

// ---------------- flash attention: barrier-free, LDS-free K/V streaming ----------------
// K/V for one (b,h) = 512 KB, and all 16 q-tile blocks of a head share one XCD (bh
// contains ii&7) -> K/V is L2-resident. MFMA fragments are loaded DIRECTLY from global
// (operand values bit-identical to the old LDS path: the write/read swizzles cancel).
// No K/V LDS, no global_load_lds, no barriers in the main loop; 16 waves/CU TLP +
// compiler pipelining hide L1/L2 latency. LDS keeps only epilogue scratch + lutS.
__global__ __launch_bounds__(512, 4) void attn_kernel(const unsigned short* __restrict__ Qb,
                                                      const unsigned short* __restrict__ Kb,
                                                      const unsigned short* __restrict__ Vtb,
                                                      const float* __restrict__ lut,
                                                      unsigned short* __restrict__ Ob) {
  __shared__ float OxS[4][2048];   // epilogue half-merge scratch (32 KB)
  __shared__ float lutS[512];      // bias window; reused as lpf in epilogue
  const int tid = threadIdx.x;
  const int wave = tid >> 6, lane = tid & 63;
  const int quad = lane >> 4, lm = lane & 15;
  const int ws = wave & 3, half = wave >> 2;
  const int ii = blockIdx.x;
  const int bh = (ii & 7) * 4 + ((ii >> 3) & 3);
  const int qTile = (ii >> 5) * 128;
  const int b = bh >> 4, h = bh & 15;
  const unsigned short* Qp = Qb + (size_t)bh * S_LEN * 64;
  const unsigned short* Kp = Kb + (size_t)bh * S_LEN * 64;
  const unsigned short* Vp = Vtb + (size_t)bh * 64 * S_LEN;
  const float* lrow = lut + h * 4096;
  const float cneg = lrow[0] * L2E, cpos = lrow[4095] * L2E;
  const int qw = qTile + ws * 32;
  // permuted A-row (swap bits 2,3 of lm) and matching k-offset for this quad
  const int lmP = (lm & 3) | ((lm & 4) << 1) | ((lm & 8) >> 1);
  const int qq4 = ((quad & 1) << 3) | ((quad & 2) << 1);  // = swap23(quad*4)

  lutS[tid & 511] = lrow[2048 - 256 + (tid & 511)] * L2E;

  // per-lane K/V fragment base pointers (direct-global MFMA operands)
  const unsigned short* kA = Kp + lmP * 64 + quad * 8;
  const unsigned short* vA = Vp + lm * S_LEN + quad * 8;

  bf16x8 aq[2][2];
#pragma unroll
  for (int g = 0; g < 2; g++)
#pragma unroll
    for (int hh = 0; hh < 2; hh++)
      aq[g][hh] = *(const bf16x8*)&Qp[(qw + g * 16 + lm) * 64 + hh * 32 + quad * 8];

  floatx4 accO[2][4];
#pragma unroll
  for (int g = 0; g < 2; g++)
#pragma unroll
    for (int d = 0; d < 4; d++) accO[g][d] = (floatx4){0.f, 0.f, 0.f, 0.f};
  float lp[2] = {0.f, 0.f};

  __syncthreads();  // lutS visible to all waves; the only pre-epilogue barrier

  for (int ktl = 0; ktl < 32; ktl++) {
    const int kBase = (half << 10) + ktl * 32;

    // K fragments for this tile, direct from global (L1/L2-hit)
    bf16x8 kf00 = *(const bf16x8*)&kA[(size_t)kBase * 64];
    bf16x8 kf01 = *(const bf16x8*)&kA[(size_t)kBase * 64 + 32];
    bf16x8 kf10 = *(const bf16x8*)&kA[(size_t)(kBase + 16) * 64];
    bf16x8 kf11 = *(const bf16x8*)&kA[(size_t)(kBase + 16) * 64 + 32];
    // V fragments
    bf16x8 vf0 = *(const bf16x8*)&vA[kBase];
    bf16x8 vf1 = *(const bf16x8*)&vA[16 * S_LEN + kBase];
    bf16x8 vf2 = *(const bf16x8*)&vA[32 * S_LEN + kBase];
    bf16x8 vf3 = *(const bf16x8*)&vA[48 * S_LEN + kBase];

    const bool farTile = (kBase + 122 <= qTile) || (kBase >= qTile + 218);
    const float cfar = (kBase < qTile) ? cneg : cpos;

    floatx4 s4[2][2];
    __builtin_amdgcn_s_setprio(1);
#pragma unroll
    for (int g = 0; g < 2; g++) {
      floatx4 z = (floatx4){0.f, 0.f, 0.f, 0.f};
      z = __builtin_amdgcn_mfma_f32_16x16x32_bf16(kf00, aq[g][0], z, 0, 0, 0);
      z = __builtin_amdgcn_mfma_f32_16x16x32_bf16(kf01, aq[g][1], z, 0, 0, 0);
      s4[g][0] = z;
      floatx4 z2 = (floatx4){0.f, 0.f, 0.f, 0.f};
      z2 = __builtin_amdgcn_mfma_f32_16x16x32_bf16(kf10, aq[g][0], z2, 0, 0, 0);
      z2 = __builtin_amdgcn_mfma_f32_16x16x32_bf16(kf11, aq[g][1], z2, 0, 0, 0);
      s4[g][1] = z2;
    }
    __builtin_amdgcn_s_setprio(0);

    bf16x8 pa[2];
#pragma unroll
    for (int g = 0; g < 2; g++) {
      const int b0 = kBase + qq4 - (qw + g * 16 + lm) + 256;
      float psum = 0.f;
      unsigned w00, w01, w10, w11;
#pragma unroll
      for (int nt = 0; nt < 2; nt++) {
        float sv0, sv1, sv2, sv3;
        if (farTile) {
          sv0 = s4[g][nt][0] + cfar; sv1 = s4[g][nt][1] + cfar;
          sv2 = s4[g][nt][2] + cfar; sv3 = s4[g][nt][3] + cfar;
        } else {
          const float* lb = &lutS[b0 + nt * 16];
          sv0 = s4[g][nt][0] + lb[0]; sv1 = s4[g][nt][1] + lb[1];
          sv2 = s4[g][nt][2] + lb[2]; sv3 = s4[g][nt][3] + lb[3];
        }
        float p0 = __builtin_amdgcn_exp2f(sv0);
        float p1 = __builtin_amdgcn_exp2f(sv1);
        float p2 = __builtin_amdgcn_exp2f(sv2);
        float p3 = __builtin_amdgcn_exp2f(sv3);
        psum += (p0 + p1) + (p2 + p3);
        unsigned wlo, whi;
        asm("v_cvt_pk_bf16_f32 %0, %1, %2" : "=v"(wlo) : "v"(p0), "v"(p1));
        asm("v_cvt_pk_bf16_f32 %0, %1, %2" : "=v"(whi) : "v"(p2), "v"(p3));
        if (nt == 0) { w00 = wlo; w01 = whi; } else { w10 = wlo; w11 = whi; }
      }
      lp[g] += psum;
      // lane^32 exchange: after this, w00/w01 = pa words 0/1, w10/w11 = pa words 2/3
      asm("v_permlane32_swap_b32 %0, %1" : "+v"(w00), "+v"(w10));
      asm("v_permlane32_swap_b32 %0, %1" : "+v"(w01), "+v"(w11));
      union { unsigned u[4]; bf16x8 v; } pk;
      pk.u[0] = w00; pk.u[1] = w01; pk.u[2] = w10; pk.u[3] = w11;
      pa[g] = pk.v;
    }

    __builtin_amdgcn_s_setprio(1);
    accO[0][0] = __builtin_amdgcn_mfma_f32_16x16x32_bf16(pa[0], vf0, accO[0][0], 0, 0, 0);
    accO[1][0] = __builtin_amdgcn_mfma_f32_16x16x32_bf16(pa[1], vf0, accO[1][0], 0, 0, 0);
    accO[0][1] = __builtin_amdgcn_mfma_f32_16x16x32_bf16(pa[0], vf1, accO[0][1], 0, 0, 0);
    accO[1][1] = __builtin_amdgcn_mfma_f32_16x16x32_bf16(pa[1], vf1, accO[1][1], 0, 0, 0);
    accO[0][2] = __builtin_amdgcn_mfma_f32_16x16x32_bf16(pa[0], vf2, accO[0][2], 0, 0, 0);
    accO[1][2] = __builtin_amdgcn_mfma_f32_16x16x32_bf16(pa[1], vf2, accO[1][2], 0, 0, 0);
    accO[0][3] = __builtin_amdgcn_mfma_f32_16x16x32_bf16(pa[0], vf3, accO[0][3], 0, 0, 0);
    accO[1][3] = __builtin_amdgcn_mfma_f32_16x16x32_bf16(pa[1], vf3, accO[1][3], 0, 0, 0);
    __builtin_amdgcn_s_setprio(0);
  }

#pragma unroll
  for (int g = 0; g < 2; g++) {
    lp[g] += __shfl_xor(lp[g], 16, 64);
    lp[g] += __shfl_xor(lp[g], 32, 64);
  }

  __syncthreads();
  float* Ox = &OxS[ws][0];
  float* lpf = lutS;  // lutS dead after the loop; reuse as the lp exchange buffer
  if (half == 1) {
#pragma unroll
    for (int g = 0; g < 2; g++) {
#pragma unroll
      for (int d = 0; d < 4; d++)
#pragma unroll
        for (int r = 0; r < 4; r++)
          Ox[(g * 16 + quad * 4 + r) * 64 + d * 16 + lm] = accO[g][d][r];
      if (quad == 0) lpf[ws * 32 + g * 16 + lm] = lp[g];
    }
  }
  __syncthreads();
  if (half == 0) {
    float ltot[2];
#pragma unroll
    for (int g = 0; g < 2; g++) ltot[g] = lp[g] + lpf[ws * 32 + g * 16 + lm];
#pragma unroll
    for (int g = 0; g < 2; g++) {
      float linv[4];
#pragma unroll
      for (int r = 0; r < 4; r++) linv[r] = 1.f / __shfl(ltot[g], quad * 4 + r, 64);
#pragma unroll
      for (int d = 0; d < 4; d++)
#pragma unroll
        for (int r = 0; r < 4; r++) {
          float val = accO[g][d][r] + Ox[(g * 16 + quad * 4 + r) * 64 + d * 16 + lm];
          int q = qw + g * 16 + quad * 4 + r;
          int col = h * 64 + d * 16 + lm;
          Ob[((size_t)(b * S_LEN + q)) * 1024 + col] = f2bf_fast(val * linv[r]);
        }
    }
  }
}

extern "C" void kernel_launch(void* const* d_in, const int* in_sizes, int n_in,
                              void* d_out, int out_size, void* d_ws, size_t ws_size,
                              hipStream_t stream) {
  const float* X   = (const float*)d_in[0];
  const float* Wq  = (const float*)d_in[1];
  const float* Wk  = (const float*)d_in[2];
  const float* Wv  = (const float*)d_in[3];
  const float* Wo  = (const float*)d_in[4];
  const float* rel = (const float*)d_in[5];
  float* out = (float*)d_out;           // [2,2048,1024]
  float* bias_out = out + 4194304;      // [1,16,2048,2048]

  char* ws = (char*)d_ws;
  unsigned short* Xb  = (unsigned short*)(ws);
  unsigned short* WT  = (unsigned short*)(ws + (size_t)(8u << 20));   // Wq|Wk|Wv|Wo transposed
  unsigned short* Qb  = (unsigned short*)(ws + (size_t)(16u << 20));
  unsigned short* Kb  = (unsigned short*)(ws + (size_t)(24u << 20));
  unsigned short* Vtb = (unsigned short*)(ws + (size_t)(32u << 20));
  unsigned short* Ob  = (unsigned short*)(ws + (size_t)(40u << 20));
  float* lut          = (float*)(ws + (size_t)(48u << 20));

  prep_kernel<<<8208, 256, 0, stream>>>(X, Wq, Wk, Wv, Wo, rel, Xb, WT, lut);
  gemm_qkv<<<928, 256, 0, stream>>>(Xb, WT, Qb, Kb, Vtb, lut, bias_out);
  attn_kernel<<<512, 512, 0, stream>>>(Qb, Kb, Vtb, lut, Ob);
  gemm_out<<<352, 256, 0, stream>>>(Ob, WT + 3 * 1048576, out, lut, bias_out);
}

// Round 4
// 386.503 us; speedup vs baseline: 1.2263x; 1.2263x over previous
//
#include <hip/hip_runtime.h>
#include <stdint.h>

#define S_LEN 2048
#define NH 16
#define EMB 1024
#define L2E 1.44269504f

typedef __attribute__((ext_vector_type(8))) short bf16x8;
typedef __attribute__((ext_vector_type(4))) float floatx4;
typedef const __attribute__((address_space(1))) unsigned int* gas_u32p;
typedef __attribute__((address_space(3))) unsigned int* las_u32p;

static __device__ __forceinline__ void gld_lds16(const void* g, void* l) {
  __builtin_amdgcn_global_load_lds((gas_u32p)g, (las_u32p)l, 16, 0, 0);
}

static __device__ __forceinline__ unsigned short f2bf(float f) {
  unsigned int u = __float_as_uint(f);
  unsigned int r = (u + 0x7FFFu + ((u >> 16) & 1u)) >> 16;
  return (unsigned short)r;
}
static __device__ __forceinline__ unsigned short f2bf_fast(float f) {
  return (unsigned short)((__float_as_uint(f) + 0x8000u) >> 16);
}

// ---------------- fused prep: cast X, transpose 4 weights, build LUT ----------------
__global__ __launch_bounds__(256) void prep_kernel(const float* __restrict__ X,
                                                   const float* __restrict__ Wq,
                                                   const float* __restrict__ Wk,
                                                   const float* __restrict__ Wv,
                                                   const float* __restrict__ Wo,
                                                   const float* __restrict__ rel,
                                                   unsigned short* __restrict__ Xb,
                                                   unsigned short* __restrict__ WT,
                                                   float* __restrict__ lut) {
  __shared__ float tile[32][33];
  const int bid = blockIdx.x, tid = threadIdx.x;
  if (bid < 4096) {
    int i = bid * 256 + tid;
    float4 v = ((const float4*)X)[i];
    ushort4 o;
    o.x = f2bf(v.x); o.y = f2bf(v.y); o.z = f2bf(v.z); o.w = f2bf(v.w);
    ((ushort4*)Xb)[i] = o;
  } else if (bid < 8192) {
    int w = (bid - 4096) >> 10, t = (bid - 4096) & 1023;
    const float* in = (w == 0) ? Wq : (w == 1) ? Wk : (w == 2) ? Wv : Wo;
    unsigned short* o = WT + (size_t)w * 1048576;
    int bx = t & 31, by = t >> 5;
    int tx = tid & 31, ty = tid >> 5;
    int x = bx * 32 + tx, y0 = by * 32 + ty;
#pragma unroll
    for (int j = 0; j < 4; j++)
      tile[ty + 8 * j][tx] = in[(y0 + 8 * j) * EMB + x];
    __syncthreads();
    int x2 = by * 32 + tx, y2 = bx * 32 + ty;
#pragma unroll
    for (int j = 0; j < 4; j++)
      o[(y2 + 8 * j) * EMB + x2] = f2bf(tile[tx][ty + 8 * j]);
  } else {
    int idx = (bid - 8192) * 256 + tid;
    int delta = idx - 2048;
    int bucket = (delta > 0) ? 16 : 0;
    int rp = (delta < 0) ? -delta : delta;
    int bl;
    if (rp < 8) bl = rp;
    else bl = 8 + (rp >= 12) + (rp >= 16) + (rp >= 23) + (rp >= 32) + (rp >= 46) + (rp >= 64) + (rp >= 91);
    bucket += bl;
#pragma unroll
    for (int h = 0; h < NH; h++)
      lut[h * 4096 + idx] = rel[bucket * NH + h];
  }
}

// ---------------- QKV GEMM (pure; bias writer moved into attn) ----------------
__global__ __launch_bounds__(256) void gemm_qkv(const unsigned short* __restrict__ A,
                                                const unsigned short* __restrict__ BT,
                                                unsigned short* __restrict__ oQ,
                                                unsigned short* __restrict__ oK,
                                                unsigned short* __restrict__ oV) {
  __shared__ __align__(16) unsigned short As[128 * 64];
  __shared__ __align__(16) unsigned short Bs[128 * 64];
  const int tid = threadIdx.x;
  const int id = blockIdx.x;
  const int wave = tid >> 6, lane = tid & 63;
  const int quad = lane >> 4, lm = lane & 15;
  const int wm = wave & 1, wn = wave >> 1;
  // XCD-aware chunked remap: 768 = 8 xcd * 96; same-mBase blocks land on one XCD's L2
  const int id2 = (id & 7) * 96 + (id >> 3);
  const int mBase = (id2 / 24) * 128, nBase = (id2 % 24) * 128;
  const int gg = (lane & 7) ^ (lane >> 3);
  const int srow = lane >> 3;
  floatx4 acc[4][4];
#pragma unroll
  for (int i = 0; i < 4; i++)
#pragma unroll
    for (int j = 0; j < 4; j++) acc[i][j] = (floatx4){0.f, 0.f, 0.f, 0.f};

  for (int kt = 0; kt < 16; kt++) {
    int k0 = kt * 64;
    __syncthreads();
#pragma unroll
    for (int c = 0; c < 4; c++) {
      int chunk = wave * 4 + c;
      int row = chunk * 8 + srow;
      gld_lds16(&A[(size_t)(mBase + row) * 1024 + k0 + gg * 8], &As[chunk * 512]);
      gld_lds16(&BT[(size_t)(nBase + row) * 1024 + k0 + gg * 8], &Bs[chunk * 512]);
    }
    __syncthreads();
#pragma unroll
    for (int hh = 0; hh < 2; hh++) {
      bf16x8 af[4], bfr[4];
#pragma unroll
      for (int i = 0; i < 4; i++)
        af[i] = *(const bf16x8*)&As[(wm * 64 + i * 16 + lm) * 64 + (((hh << 2) + quad) ^ (lm & 7)) * 8];
#pragma unroll
      for (int j = 0; j < 4; j++)
        bfr[j] = *(const bf16x8*)&Bs[(wn * 64 + j * 16 + lm) * 64 + (((hh << 2) + quad) ^ (lm & 7)) * 8];
#pragma unroll
      for (int i = 0; i < 4; i++)
#pragma unroll
        for (int j = 0; j < 4; j++)
          acc[i][j] = __builtin_amdgcn_mfma_f32_16x16x32_bf16(af[i], bfr[j], acc[i][j], 0, 0, 0);
    }
  }
  const int which = nBase >> 10;  // block-uniform
  if (which == 2) {
#pragma unroll
    for (int i = 0; i < 4; i++)
#pragma unroll
      for (int j = 0; j < 4; j++) {
        int hd = (nBase - 2048) + wn * 64 + j * 16 + lm;
        int h = hd >> 6, d = hd & 63;
        int m = mBase + wm * 64 + i * 16 + quad * 4;
        int b = m >> 11, s = m & 2047;
        union { unsigned short u[4]; uint2 v; } pk;
#pragma unroll
        for (int r = 0; r < 4; r++) pk.u[r] = f2bf(acc[i][j][r]);
        *(uint2*)&oV[(((size_t)(b * NH + h) * 64 + d) * S_LEN) + s] = pk.v;
      }
  } else {
#pragma unroll
    for (int i = 0; i < 4; i++)
#pragma unroll
      for (int j = 0; j < 4; j++)
#pragma unroll
        for (int r = 0; r < 4; r++) {
          int row = mBase + wm * 64 + i * 16 + quad * 4 + r;
          int col = nBase + wn * 64 + j * 16 + lm;
          int b = row >> 11, s = row & 2047;
          int cw = col & 1023;
          int h = cw >> 6, d = cw & 63;
          float v = acc[i][j][r];
          if (which == 0) v *= L2E;  // pre-scale Q for exp2-based softmax
          unsigned short sv = f2bf(v);
          if (which == 0) oQ[(((size_t)(b * NH + h) * S_LEN + s) * 64) + d] = sv;
          else            oK[(((size_t)(b * NH + h) * S_LEN + s) * 64) + d] = sv;
        }
  }
}

// ---------------- GEMM out-proj (pure; bias writer moved into attn) ----------------
__global__ __launch_bounds__(256) void gemm_out(const unsigned short* __restrict__ A,
                                                const unsigned short* __restrict__ BT,
                                                float* __restrict__ oF) {
  __shared__ __align__(16) unsigned short As[128 * 64];
  __shared__ __align__(16) unsigned short Bs[128 * 64];
  const int tid = threadIdx.x;
  const int id = blockIdx.x;
  const int wave = tid >> 6, lane = tid & 63;
  const int quad = lane >> 4, lm = lane & 15;
  const int wm = wave & 1, wn = wave >> 1;
  // XCD-aware chunked remap: 256 = 8 xcd * 32
  const int id2 = (id & 7) * 32 + (id >> 3);
  const int mBase = (id2 >> 3) * 128, nBase = (id2 & 7) * 128;
  const int gg = (lane & 7) ^ (lane >> 3);
  const int srow = lane >> 3;
  floatx4 acc[4][4];
#pragma unroll
  for (int i = 0; i < 4; i++)
#pragma unroll
    for (int j = 0; j < 4; j++) acc[i][j] = (floatx4){0.f, 0.f, 0.f, 0.f};

  for (int kt = 0; kt < 16; kt++) {
    int k0 = kt * 64;
    __syncthreads();
#pragma unroll
    for (int c = 0; c < 4; c++) {
      int chunk = wave * 4 + c;
      int row = chunk * 8 + srow;
      gld_lds16(&A[(size_t)(mBase + row) * 1024 + k0 + gg * 8], &As[chunk * 512]);
      gld_lds16(&BT[(size_t)(nBase + row) * 1024 + k0 + gg * 8], &Bs[chunk * 512]);
    }
    __syncthreads();
#pragma unroll
    for (int hh = 0; hh < 2; hh++) {
      bf16x8 af[4], bfr[4];
#pragma unroll
      for (int i = 0; i < 4; i++)
        af[i] = *(const bf16x8*)&As[(wm * 64 + i * 16 + lm) * 64 + (((hh << 2) + quad) ^ (lm & 7)) * 8];
#pragma unroll
      for (int j = 0; j < 4; j++)
        bfr[j] = *(const bf16x8*)&Bs[(wn * 64 + j * 16 + lm) * 64 + (((hh << 2) + quad) ^ (lm & 7)) * 8];
#pragma unroll
      for (int i = 0; i < 4; i++)
#pragma unroll
        for (int j = 0; j < 4; j++)
          acc[i][j] = __builtin_amdgcn_mfma_f32_16x16x32_bf16(af[i], bfr[j], acc[i][j], 0, 0, 0);
    }
  }
#pragma unroll
  for (int i = 0; i < 4; i++)
#pragma unroll
    for (int j = 0; j < 4; j++)
#pragma unroll
      for (int r = 0; r < 4; r++) {
        int row = mBase + wm * 64 + i * 16 + quad * 4 + r;
        int col = nBase + wn * 64 + j * 16 + lm;
        oF[(size_t)row * 1024 + col] = acc[i][j][r];
      }
}

// ---------------- flash attention (round-1 structure) + fused bias writer ----------------
// Attn is LDS/MFMA-bound with an idle HBM pipe; each thread also streams its 64 float4
// rows of position_bias (2 per k-iter) via nontemporal stores, hiding the 256 MB bias
// write under the k-loop's compute. GEMM kernels are now bias-free.
__global__ __launch_bounds__(512, 4) void attn_kernel(const unsigned short* __restrict__ Qb,
                                                      const unsigned short* __restrict__ Kb,
                                                      const unsigned short* __restrict__ Vtb,
                                                      const float* __restrict__ lut,
                                                      unsigned short* __restrict__ Ob,
                                                      float* __restrict__ bias_out) {
  __shared__ __align__(16) unsigned short Kl[2][2][2048];  // [half][buf][32 k x 64 d]
  __shared__ __align__(16) unsigned short Vl[2][2][2048];  // [half][buf][64 d x 32 k]
  __shared__ float lutS[512];                              // bias window; reused as lpf in epilogue
  const int tid = threadIdx.x;
  const int wave = tid >> 6, lane = tid & 63;
  const int quad = lane >> 4, lm = lane & 15;
  const int ws = wave & 3, half = wave >> 2;
  const int ii = blockIdx.x;
  const int bh = (ii & 7) * 4 + ((ii >> 3) & 3);
  const int qTile = (ii >> 5) * 128;
  const int b = bh >> 4, h = bh & 15;
  const unsigned short* Qp = Qb + (size_t)bh * S_LEN * 64;
  const unsigned short* Kp = Kb + (size_t)bh * S_LEN * 64;
  const unsigned short* Vp = Vtb + (size_t)bh * 64 * S_LEN;
  const float* lrow = lut + h * 4096;
  const float cneg = lrow[0] * L2E, cpos = lrow[4095] * L2E;
  const int srow = lane >> 3;
  const int gg = (lane & 7) ^ (srow & 7);
  const int vrow = lane >> 2;
  const int vgg = (lane & 3) ^ ((lane >> 3) & 3);
  const int qw = qTile + ws * 32;
  // permuted A-row (swap bits 2,3 of lm) and matching k-offset for this quad
  const int lmP = (lm & 3) | ((lm & 4) << 1) | ((lm & 8) >> 1);
  const int qq4 = ((quad & 1) << 3) | ((quad & 2) << 1);  // = swap23(quad*4)

  lutS[tid & 511] = lrow[2048 - 256 + (tid & 511)] * L2E;

  bf16x8 aq[2][2];
#pragma unroll
  for (int g = 0; g < 2; g++)
#pragma unroll
    for (int hh = 0; hh < 2; hh++)
      aq[g][hh] = *(const bf16x8*)&Qp[(qw + g * 16 + lm) * 64 + hh * 32 + quad * 8];

  floatx4 accO[2][4];
#pragma unroll
  for (int g = 0; g < 2; g++)
#pragma unroll
    for (int d = 0; d < 4; d++) accO[g][d] = (floatx4){0.f, 0.f, 0.f, 0.f};
  float lp[2] = {0.f, 0.f};

  const int vswz = ((lm >> 1) & 3);

  {
    const int kBase = half << 10;
    gld_lds16(&Kp[(size_t)(kBase + ws * 8 + srow) * 64 + gg * 8], &Kl[half][0][ws * 512]);
    gld_lds16(&Vp[(size_t)(ws * 16 + vrow) * S_LEN + kBase + vgg * 8], &Vl[half][0][ws * 512]);
  }

  for (int ktl = 0; ktl < 32; ktl++) {
    const int buf = ktl & 1;
    const int kBase = (half << 10) + ktl * 32;
    __syncthreads();
    if (ktl < 31) {
      const int kn = kBase + 32;
      gld_lds16(&Kp[(size_t)(kn + ws * 8 + srow) * 64 + gg * 8], &Kl[half][buf ^ 1][ws * 512]);
      gld_lds16(&Vp[(size_t)(ws * 16 + vrow) * S_LEN + kn + vgg * 8], &Vl[half][buf ^ 1][ws * 512]);
    }
    const unsigned short* Kbuf = Kl[half][buf];
    const unsigned short* Vbuf = Vl[half][buf];

    const bool farTile = (kBase + 122 <= qTile) || (kBase >= qTile + 218);
    const float cfar = (kBase < qTile) ? cneg : cpos;

    floatx4 s4[2][2];
    __builtin_amdgcn_s_setprio(1);
#pragma unroll
    for (int nt = 0; nt < 2; nt++) {
      int rbase = (nt * 16 + lmP) * 64;
      bf16x8 kf0 = *(const bf16x8*)&Kbuf[rbase + ((quad ^ (lmP & 7)) << 3)];
      bf16x8 kf1 = *(const bf16x8*)&Kbuf[rbase + (((4 + quad) ^ (lmP & 7)) << 3)];
#pragma unroll
      for (int g = 0; g < 2; g++) {
        floatx4 z = (floatx4){0.f, 0.f, 0.f, 0.f};
        z = __builtin_amdgcn_mfma_f32_16x16x32_bf16(kf0, aq[g][0], z, 0, 0, 0);
        z = __builtin_amdgcn_mfma_f32_16x16x32_bf16(kf1, aq[g][1], z, 0, 0, 0);
        s4[g][nt] = z;
      }
    }
    __builtin_amdgcn_s_setprio(0);

    bf16x8 pa[2];
#pragma unroll
    for (int g = 0; g < 2; g++) {
      const int b0 = kBase + qq4 - (qw + g * 16 + lm) + 256;
      float psum = 0.f;
      unsigned w00, w01, w10, w11;
#pragma unroll
      for (int nt = 0; nt < 2; nt++) {
        float sv0, sv1, sv2, sv3;
        if (farTile) {
          sv0 = s4[g][nt][0] + cfar; sv1 = s4[g][nt][1] + cfar;
          sv2 = s4[g][nt][2] + cfar; sv3 = s4[g][nt][3] + cfar;
        } else {
          const float* lb = &lutS[b0 + nt * 16];
          sv0 = s4[g][nt][0] + lb[0]; sv1 = s4[g][nt][1] + lb[1];
          sv2 = s4[g][nt][2] + lb[2]; sv3 = s4[g][nt][3] + lb[3];
        }
        float p0 = __builtin_amdgcn_exp2f(sv0);
        float p1 = __builtin_amdgcn_exp2f(sv1);
        float p2 = __builtin_amdgcn_exp2f(sv2);
        float p3 = __builtin_amdgcn_exp2f(sv3);
        psum += (p0 + p1) + (p2 + p3);
        unsigned wlo, whi;
        asm("v_cvt_pk_bf16_f32 %0, %1, %2" : "=v"(wlo) : "v"(p0), "v"(p1));
        asm("v_cvt_pk_bf16_f32 %0, %1, %2" : "=v"(whi) : "v"(p2), "v"(p3));
        if (nt == 0) { w00 = wlo; w01 = whi; } else { w10 = wlo; w11 = whi; }
      }
      lp[g] += psum;
      // lane^32 exchange: after this, w00/w01 = pa words 0/1, w10/w11 = pa words 2/3
      asm("v_permlane32_swap_b32 %0, %1" : "+v"(w00), "+v"(w10));
      asm("v_permlane32_swap_b32 %0, %1" : "+v"(w01), "+v"(w11));
      union { unsigned u[4]; bf16x8 v; } pk;
      pk.u[0] = w00; pk.u[1] = w01; pk.u[2] = w10; pk.u[3] = w11;
      pa[g] = pk.v;
    }

    __builtin_amdgcn_s_setprio(1);
#pragma unroll
    for (int d = 0; d < 4; d++) {
      bf16x8 vf = *(const bf16x8*)&Vbuf[(d * 16 + lm) * 32 + ((quad ^ vswz) << 3)];
      accO[0][d] = __builtin_amdgcn_mfma_f32_16x16x32_bf16(pa[0], vf, accO[0][d], 0, 0, 0);
      accO[1][d] = __builtin_amdgcn_mfma_f32_16x16x32_bf16(pa[1], vf, accO[1][d], 0, 0, 0);
    }
    __builtin_amdgcn_s_setprio(0);

    // fused bias writer: 2 float4 rows/iter/thread, hidden under compute (HBM idle here)
#pragma unroll
    for (int u = 0; u < 2; u++) {
      int e = ktl * 2 + u;
      int i = (ii << 15) + (e << 9) + tid;
      int hb = i >> 20;
      int rem = i & 1048575;
      int q = rem >> 9;
      int k4 = (rem & 511) << 2;
      const float* lr = lut + hb * 4096 + (k4 - q + 2048);
      floatx4 bv = (floatx4){lr[0], lr[1], lr[2], lr[3]};
      __builtin_nontemporal_store(bv, (floatx4*)&bias_out[(size_t)i * 4]);
    }
  }

#pragma unroll
  for (int g = 0; g < 2; g++) {
    lp[g] += __shfl_xor(lp[g], 16, 64);
    lp[g] += __shfl_xor(lp[g], 32, 64);
  }

  __syncthreads();
  float* Ox = (ws < 2) ? ((float*)&Kl[0][0][0]) + ws * 2048 : ((float*)&Vl[0][0][0]) + (ws - 2) * 2048;
  float* lpf = lutS;  // lutS dead after the loop; reuse as the lp exchange buffer
  if (half == 1) {
#pragma unroll
    for (int g = 0; g < 2; g++) {
#pragma unroll
      for (int d = 0; d < 4; d++)
#pragma unroll
        for (int r = 0; r < 4; r++)
          Ox[(g * 16 + quad * 4 + r) * 64 + d * 16 + lm] = accO[g][d][r];
      if (quad == 0) lpf[ws * 32 + g * 16 + lm] = lp[g];
    }
  }
  __syncthreads();
  if (half == 0) {
    float ltot[2];
#pragma unroll
    for (int g = 0; g < 2; g++) ltot[g] = lp[g] + lpf[ws * 32 + g * 16 + lm];
#pragma unroll
    for (int g = 0; g < 2; g++) {
      float linv[4];
#pragma unroll
      for (int r = 0; r < 4; r++) linv[r] = 1.f / __shfl(ltot[g], quad * 4 + r, 64);
#pragma unroll
      for (int d = 0; d < 4; d++)
#pragma unroll
        for (int r = 0; r < 4; r++) {
          float val = accO[g][d][r] + Ox[(g * 16 + quad * 4 + r) * 64 + d * 16 + lm];
          int q = qw + g * 16 + quad * 4 + r;
          int col = h * 64 + d * 16 + lm;
          Ob[((size_t)(b * S_LEN + q)) * 1024 + col] = f2bf_fast(val * linv[r]);
        }
    }
  }
}

extern "C" void kernel_launch(void* const* d_in, const int* in_sizes, int n_in,
                              void* d_out, int out_size, void* d_ws, size_t ws_size,
                              hipStream_t stream) {
  const float* X   = (const float*)d_in[0];
  const float* Wq  = (const float*)d_in[1];
  const float* Wk  = (const float*)d_in[2];
  const float* Wv  = (const float*)d_in[3];
  const float* Wo  = (const float*)d_in[4];
  const float* rel = (const float*)d_in[5];
  float* out = (float*)d_out;           // [2,2048,1024]
  float* bias_out = out + 4194304;      // [1,16,2048,2048]

  char* ws = (char*)d_ws;
  unsigned short* Xb  = (unsigned short*)(ws);
  unsigned short* WT  = (unsigned short*)(ws + (size_t)(8u << 20));   // Wq|Wk|Wv|Wo transposed
  unsigned short* Qb  = (unsigned short*)(ws + (size_t)(16u << 20));
  unsigned short* Kb  = (unsigned short*)(ws + (size_t)(24u << 20));
  unsigned short* Vtb = (unsigned short*)(ws + (size_t)(32u << 20));
  unsigned short* Ob  = (unsigned short*)(ws + (size_t)(40u << 20));
  float* lut          = (float*)(ws + (size_t)(48u << 20));

  prep_kernel<<<8208, 256, 0, stream>>>(X, Wq, Wk, Wv, Wo, rel, Xb, WT, lut);
  gemm_qkv<<<768, 256, 0, stream>>>(Xb, WT, Qb, Kb, Vtb);
  attn_kernel<<<512, 512, 0, stream>>>(Qb, Kb, Vtb, lut, Ob, bias_out);
  gemm_out<<<256, 256, 0, stream>>>(Ob, WT + 3 * 1048576, out);
}